// Round 3
// baseline (276.640 us; speedup 1.0000x reference)
//
#include <hip/hip_runtime.h>
#include <hip/hip_bf16.h>
#include <string.h>

typedef __attribute__((ext_vector_type(8))) short short8;
typedef __attribute__((ext_vector_type(4))) float floatx4;

// B=32, T=2048, D=512, U=512, M = B*T = 65536

__device__ inline uint packbf2(float lo, float hi) {
    __hip_bfloat162 h = __float22bfloat162_rn(make_float2(lo, hi));
    uint r; memcpy(&r, &h, 4); return r;
}

__device__ inline float tanh_fast(float x) {
    x = fminf(15.f, fmaxf(-15.f, x));
    float e = __expf(2.f * x);
    return __fdividef(e - 1.f, e + 1.f);
}

// LDS-visibility-only barrier: waits LDS ops, does NOT drain vmcnt, so
// outstanding global->register prefetch loads stay in flight across it.
__device__ inline void barrier_lgkm() {
    asm volatile("s_waitcnt lgkmcnt(0)\n\ts_barrier" ::: "memory");
}

// ---- kernel 0: fused prep. blocks 0..127: pack W1_enc -> bf16 B-frag chunks.
//                blocks 128..383: dec[b][u] = h_dec[b]·W1_dec[:,u] + b1[u]
__global__ void kprep(const float* __restrict__ W1, const float* __restrict__ hdec,
                      const float* __restrict__ b1, ushort* __restrict__ Wp,
                      float* __restrict__ dec) {
    __shared__ float red[4][64];
    int tid = threadIdx.x;
    if (blockIdx.x < 128) {
        int wid = blockIdx.x * 4 + (tid >> 6);       // 0..511 chunks
        int l = tid & 63;
        int kc = wid >> 5, ng = wid & 31;
        int m = l & 15, g = l >> 4;
        const float* src = W1 + (size_t)(kc * 32 + g * 8) * 512 + ng * 16 + m;
        uint u4[4];
        #pragma unroll
        for (int e = 0; e < 4; ++e)
            u4[e] = packbf2(src[(size_t)(2 * e) * 512], src[(size_t)(2 * e + 1) * 512]);
        *(uint4*)(Wp + (size_t)wid * 512 + l * 8) = *(uint4*)u4;
    } else {
        int bid = blockIdx.x - 128;                  // 0..255
        int b = bid >> 3, ug = bid & 7;
        int u = ug * 64 + (tid & 63), dq = tid >> 6;
        const float* hb = hdec + b * 512 + dq * 128;
        const float* w = W1 + (size_t)(512 + dq * 128) * 512 + u;
        float a = 0.f;
        #pragma unroll 8
        for (int d = 0; d < 128; ++d)
            a += hb[d] * w[(size_t)d * 512];
        red[dq][tid & 63] = a;
        __syncthreads();
        if (tid < 64)
            dec[b * 512 + ug * 64 + tid] =
                red[0][tid] + red[1][tid] + red[2][tid] + red[3][tid] + b1[ug * 64 + tid];
    }
}

// ---- kernel 1: fused GEMM + tanh + dot(W2) -> e2 (pre-relu logits)
// 512 thr = 8 waves; block tile 64 rows x 512 cols (full U) x K=512.
// K in 4 chunks of 128, double-buffered LDS; per chunk:
//   write(cc+1 from regs) -> issue loads(cc+2) -> compute(cc) -> lgkm-barrier
// The lgkm-only barrier keeps prefetch loads in flight across chunk
// boundaries (counted vmcnt emerges naturally at the next write's wait).
// j-streamed bfr keeps arch-VGPR pressure low enough for zero spill at
// launch_bounds(512,4).
__global__ __launch_bounds__(512, 4) void kgemm(
        const float* __restrict__ A, const ushort* __restrict__ Wp,
        const float* __restrict__ dec, const float* __restrict__ W2,
        float* __restrict__ e2) {
    __shared__ __align__(16) ushort Ab[2][8192];     // 2 x 16 KB (16 slots x 512)
    __shared__ float red[8][64];
    const int tid = threadIdx.x;
    const int rowbase = blockIdx.x * 64;
    const int bIdx = blockIdx.x >> 5;                // 32 blocks per batch
    const int lane = tid & 63, wave = tid >> 6;
    const int m = lane & 15, g = lane >> 4;

    // staging: thread handles slots {wave, wave+8}; slot = i*4 + kc4
    const int s0 = wave, s1 = wave + 8;
    const float* tb0 = A + (size_t)(rowbase + (s0 >> 2) * 16 + m) * 512 + (s0 & 3) * 32 + g * 8;
    const float* tb1 = A + (size_t)(rowbase + (s1 >> 2) * 16 + m) * 512 + (s1 & 3) * 32 + g * 8;

    float4 L[4];
    auto loadc = [&](int c) {                        // issue 4 float4 loads, no wait
        L[0] = *(const float4*)(tb0 + c * 128);
        L[1] = *(const float4*)(tb0 + c * 128 + 4);
        L[2] = *(const float4*)(tb1 + c * 128);
        L[3] = *(const float4*)(tb1 + c * 128 + 4);
    };
    auto writec = [&](int cb) {                      // cvt + LDS write of L
        uint4 u0, u1;
        u0.x = packbf2(L[0].x, L[0].y); u0.y = packbf2(L[0].z, L[0].w);
        u0.z = packbf2(L[1].x, L[1].y); u0.w = packbf2(L[1].z, L[1].w);
        u1.x = packbf2(L[2].x, L[2].y); u1.y = packbf2(L[2].z, L[2].w);
        u1.z = packbf2(L[3].x, L[3].y); u1.w = packbf2(L[3].z, L[3].w);
        *(uint4*)&Ab[cb][s0 * 512 + lane * 8] = u0;
        *(uint4*)&Ab[cb][s1 * 512 + lane * 8] = u1;
    };

    floatx4 acc[4][4];
    #pragma unroll
    for (int i = 0; i < 4; i++)
        #pragma unroll
        for (int j = 0; j < 4; j++) acc[i][j] = (floatx4){0.f, 0.f, 0.f, 0.f};

    const int ng0 = wave * 4;
    const ushort* wpb = Wp + (size_t)ng0 * 512 + lane * 8;

    auto compute = [&](int cc, int cb) {
        #pragma unroll
        for (int s = 0; s < 4; ++s) {
            const int kc = cc * 4 + s;
            short8 afr[4];
            #pragma unroll
            for (int i = 0; i < 4; ++i)
                afr[i] = *(const short8*)&Ab[cb][(i * 4 + s) * 512 + lane * 8];
            #pragma unroll
            for (int j = 0; j < 4; ++j) {
                short8 bfr = *(const short8*)&wpb[(size_t)(kc * 32 + j) * 512];
                #pragma unroll
                for (int i = 0; i < 4; ++i)
                    acc[i][j] = __builtin_amdgcn_mfma_f32_16x16x32_bf16(afr[i], bfr, acc[i][j], 0, 0, 0);
            }
        }
    };

    // prologue
    loadc(0);
    writec(0);
    loadc(1);
    barrier_lgkm();
    // cc = 0
    writec(1); loadc(2);
    compute(0, 0);
    barrier_lgkm();
    // cc = 1
    writec(0); loadc(3);
    compute(1, 1);
    barrier_lgkm();
    // cc = 2
    writec(1);
    compute(2, 0);
    barrier_lgkm();
    // cc = 3
    compute(3, 1);

    // epilogue: z += dec; p = sum_u tanh(z)*W2[u]; reduce 16 lanes + 8 waves
    float w2v[4], dv[4];
    #pragma unroll
    for (int j = 0; j < 4; j++) {
        int n = wave * 64 + j * 16 + m;
        w2v[j] = W2[n];
        dv[j]  = dec[bIdx * 512 + n];
    }
    #pragma unroll
    for (int i = 0; i < 4; i++) {
        #pragma unroll
        for (int r = 0; r < 4; r++) {
            float p = 0.f;
            #pragma unroll
            for (int j = 0; j < 4; j++)
                p += tanh_fast(acc[i][j][r] + dv[j]) * w2v[j];
            p += __shfl_xor(p, 1, 16);
            p += __shfl_xor(p, 2, 16);
            p += __shfl_xor(p, 4, 16);
            p += __shfl_xor(p, 8, 16);
            if (m == 0) red[wave][i * 16 + g * 4 + r] = p;
        }
    }
    __syncthreads();
    if (tid < 64) {
        float s = 0.f;
        #pragma unroll
        for (int w = 0; w < 8; ++w) s += red[w][tid];
        e2[rowbase + tid] = s;
    }
}

// ---- kernel 2: fused softmax + partial context.
// Block (b,ch): recompute row softmax stats from e2 (max is bitwise-identical
// across blocks; fmax/add order fixed), write own 64-wide attn slice, then
// part[b][ch][d] = sum_{t in chunk} attn*h_enc.
__global__ __launch_bounds__(512) void kctx2(const float* __restrict__ A,
        const float* __restrict__ e2, const float* __restrict__ b2,
        float* __restrict__ attn, float* __restrict__ part) {
    __shared__ float at[64];
    __shared__ float4 red[3][128];
    __shared__ float smax[8], ssum[8];
    int b = blockIdx.x, ch = blockIdx.y, tid = threadIdx.x;
    int lane = tid & 63, wave = tid >> 6;
    float b2v = b2[0];
    const float* erow = e2 + b * 2048;

    float f[4];
    float mx = 0.f;                                   // relu values >= 0
    #pragma unroll
    for (int i = 0; i < 4; i++) {
        f[i] = fmaxf(erow[i * 512 + tid] + b2v, 0.f);
        mx = fmaxf(mx, f[i]);
    }
    #pragma unroll
    for (int off = 1; off < 64; off <<= 1) mx = fmaxf(mx, __shfl_xor(mx, off));
    if (lane == 0) smax[wave] = mx;
    __syncthreads();
    #pragma unroll
    for (int w = 0; w < 8; ++w) mx = fmaxf(mx, smax[w]);
    float s = 0.f;
    #pragma unroll
    for (int i = 0; i < 4; i++) s += __expf(f[i] - mx);
    #pragma unroll
    for (int off = 1; off < 64; off <<= 1) s += __shfl_xor(s, off);
    if (lane == 0) ssum[wave] = s;
    __syncthreads();
    s = 0.f;
    #pragma unroll
    for (int w = 0; w < 8; ++w) s += ssum[w];
    float inv = 1.f / s;

    if (tid < 64) {
        float z = fmaxf(erow[ch * 64 + tid] + b2v, 0.f);
        float a = __expf(z - mx) * inv;
        at[tid] = a;
        attn[b * 2048 + ch * 64 + tid] = a;
    }
    __syncthreads();

    int dt = tid & 127, th = tid >> 7;               // th in 0..3, 16 t each
    const float* base = A + ((size_t)b * 2048 + ch * 64 + th * 16) * 512 + dt * 4;
    const float* aw = at + th * 16;
    float4 acc = (float4){0.f, 0.f, 0.f, 0.f};
    #pragma unroll
    for (int tt = 0; tt < 16; ++tt) {
        float a = aw[tt];
        float4 h = *(const float4*)(base + (size_t)tt * 512);
        acc.x += a * h.x; acc.y += a * h.y; acc.z += a * h.z; acc.w += a * h.w;
    }
    if (th) red[th - 1][dt] = acc;
    __syncthreads();
    if (th == 0) {
        float4 o0 = red[0][dt], o1 = red[1][dt], o2 = red[2][dt];
        float4 r;
        r.x = acc.x + o0.x + o1.x + o2.x;
        r.y = acc.y + o0.y + o1.y + o2.y;
        r.z = acc.z + o0.z + o1.z + o2.z;
        r.w = acc.w + o0.w + o1.w + o2.w;
        *(float4*)(part + ((size_t)b * 32 + ch) * 512 + dt * 4) = r;
    }
}

// ---- kernel 3: ctx[b][d] = sum_ch part[b][ch][d]
__global__ void kfin(const float* __restrict__ part, float* __restrict__ ctx) {
    int idx = blockIdx.x * 256 + threadIdx.x;        // 0..16383
    int b = idx >> 9, d = idx & 511;
    const float* p = part + (size_t)b * 32 * 512 + d;
    float s = 0.f;
    #pragma unroll
    for (int cI = 0; cI < 32; ++cI) s += p[cI * 512];
    ctx[idx] = s;
}

extern "C" void kernel_launch(void* const* d_in, const int* in_sizes, int n_in,
                              void* d_out, int out_size, void* d_ws, size_t ws_size,
                              hipStream_t stream) {
    const float* h_enc = (const float*)d_in[0];
    const float* h_dec = (const float*)d_in[1];
    const float* W1    = (const float*)d_in[2];
    const float* b1    = (const float*)d_in[3];
    const float* W2    = (const float*)d_in[4];
    const float* b2    = (const float*)d_in[5];
    float* out  = (float*)d_out;
    float* ctx  = out;              // 32*512
    float* attn = out + 32 * 512;   // 32*2048

    char* ws = (char*)d_ws;
    ushort* Wp = (ushort*)ws;                                    // 512 KB
    float* dec  = (float*)(ws + (512 * 512 * 2));                // 64 KB
    float* e2   = (float*)(ws + (512 * 512 * 2) + (32 * 512 * 4));              // 256 KB
    float* part = (float*)(ws + (512 * 512 * 2) + (32 * 512 * 4) + (65536 * 4)); // 2 MB

    kprep<<<384, 256, 0, stream>>>(W1, h_dec, b1, Wp, dec);
    kgemm<<<1024, 512, 0, stream>>>(h_enc, Wp, dec, W2, e2);
    dim3 g3(32, 32);
    kctx2<<<g3, 512, 0, stream>>>(h_enc, e2, b2, attn, part);
    kfin<<<64, 256, 0, stream>>>(part, ctx);
}